// Round 5
// baseline (232.339 us; speedup 1.0000x reference)
//
#include <hip/hip_runtime.h>

#define B_   8
#define CIN  256
#define T_   4096
#define TP   4097    // padded T (row 0 = zeros, row t+1 = x[t])
#define CO   256
#define O4   1024
#define KK   512
#define NN   32768   // B_*T_
#define NCH  128     // chunks along T
#define CL   32      // chunk length

// ws layout (float offsets)
#define OFF_XHI  0           // ushort [8][4097][256]
#define OFF_XLO  4195328
#define OFF_WHI  8390656     // ushort [1024][512]
#define OFF_WLO  8652800
#define OFF_F    8914944     // float [8][4096][256]
#define OFF_IZ   17303552
#define OFF_O    25692160
#define OFF_A    34080768    // float [8][128][256]
#define OFF_B    34342912
#define OFF_C    34605056
// total 34,867,200 floats = 139.5 MB

typedef __attribute__((ext_vector_type(8))) short short8;
typedef __attribute__((ext_vector_type(4))) float floatx4;

__device__ __forceinline__ float fsig(float x)  { return 1.0f / (1.0f + __expf(-x)); }
__device__ __forceinline__ float ftanh(float x) { return 2.0f / (1.0f + __expf(-2.0f * x)) - 1.0f; }

__device__ __forceinline__ unsigned short bf16_rne(float v) {
    unsigned u = __float_as_uint(v);
    unsigned r = (u + 0x7fffu + ((u >> 16) & 1u)) >> 16;
    return (unsigned short)r;
}
__device__ __forceinline__ void split_bf16(float v, unsigned short& hi, unsigned short& lo) {
    hi = bf16_rne(v);
    float hf = __uint_as_float(((unsigned)hi) << 16);
    lo = bf16_rne(v - hf);
}

// async 16B/lane global->LDS DMA; lds base must be wave-uniform (dest = base + lane*16)
__device__ __forceinline__ void glds16(const unsigned short* g, unsigned short* l) {
    __builtin_amdgcn_global_load_lds(
        (const __attribute__((address_space(1))) unsigned*)g,
        (__attribute__((address_space(3))) unsigned*)l, 16, 0, 0);
}

// W[o=g*256+c][i][j] -> Wa[r=c*4+g][k=j*256+i], split hi/lo bf16
__global__ void convert_w_kernel(const float* __restrict__ W,
                                 unsigned short* __restrict__ Whi,
                                 unsigned short* __restrict__ Wlo) {
    int tid = blockIdx.x * 256 + threadIdx.x;   // 1024*512
    int r = tid >> 9, k = tid & 511;
    int g = r & 3, c = r >> 2;
    int j = k >> 8, i = k & 255;
    float v = W[((size_t)((g << 8) + c)) * 512 + i * 2 + j];
    unsigned short hi, lo;
    split_bf16(v, hi, lo);
    Whi[tid] = hi;
    Wlo[tid] = lo;
}

// x[b][c][t] -> Xpad[b][t+1][c] bf16 hi/lo; blocks at t0==0 also zero row 0
__global__ void convert_x_kernel(const float* __restrict__ x,
                                 unsigned short* __restrict__ Xhi,
                                 unsigned short* __restrict__ Xlo) {
    __shared__ float tile[64][68];
    int b  = blockIdx.z;
    int c0 = blockIdx.y * 64;
    int t0 = blockIdx.x * 64;
    int tid = threadIdx.x;

    {   // read: float4 along t, 16 rows per pass
        int j4 = (tid & 15) * 4, r16 = tid >> 4;
#pragma unroll
        for (int p = 0; p < 4; p++) {
            int i = p * 16 + r16;
            float4 v = *(const float4*)&x[((size_t)(b * 256 + c0 + i)) * T_ + t0 + j4];
            tile[i][j4] = v.x; tile[i][j4 + 1] = v.y;
            tile[i][j4 + 2] = v.z; tile[i][j4 + 3] = v.w;
        }
    }
    if (t0 == 0 && tid < 64) {   // zero pad row (x[-1] = 0)
        size_t z = (size_t)b * TP * 256 + c0 + tid;
        Xhi[z] = 0; Xlo[z] = 0;
    }
    __syncthreads();
    {   // write coalesced along c
        int i = tid & 63, jj = tid >> 6;
#pragma unroll
        for (int p = 0; p < 16; p++) {
            int t = jj * 16 + p;
            float v = tile[i][t];
            unsigned short hi, lo;
            split_bf16(v, hi, lo);
            size_t idx = ((size_t)b * TP + t0 + t + 1) * 256 + c0 + i;
            Xhi[idx] = hi;
            Xlo[idx] = lo;
        }
    }
}

// C[r=1024][n=32768] = Wa · Xb^T, split-bf16 MFMA (3 products), 128x128 tile, BK=32.
// K-loop: A single-buffered LDS, B double-buffered; iter i+1's DMA issued before
// iter i's MFMA block -> DMA overlaps compute, next barrier's vmcnt drain is cheap.
__launch_bounds__(256, 3)
__global__ void gemm_mfma_kernel(const unsigned short* __restrict__ Xhi,
                                 const unsigned short* __restrict__ Xlo,
                                 const unsigned short* __restrict__ Whi,
                                 const unsigned short* __restrict__ Wlo,
                                 const float* __restrict__ bias,
                                 float* __restrict__ fw,
                                 float* __restrict__ izw,
                                 float* __restrict__ ow,
                                 float* __restrict__ Aw,
                                 float* __restrict__ Bw)
{
    __shared__ float smem_f[3 * 128 * 33];               // 50,688 B
    unsigned short* smem_us = (unsigned short*)smem_f;
    unsigned short* pA_hi = smem_us;                     // [128][32] contiguous, 8 KB
    unsigned short* pA_lo = smem_us + 4096;
    unsigned short* pB_hi[2] = { smem_us + 8192,  smem_us + 16384 };
    unsigned short* pB_lo[2] = { smem_us + 12288, smem_us + 20480 };

    const int tid  = threadIdx.x;
    const int wave = tid >> 6, lane = tid & 63;
    const int q = lane >> 4, mr = lane & 15;

    // grid map: XCD(=bid%8) keeps one X-tile for all 8 r-blocks; W L2-resident
    const int bid    = blockIdx.x;
    const int n_sub  = bid & 7;
    const int r_blk  = (bid >> 3) & 7;
    const int n_blk  = (bid >> 6) * 8 + n_sub;
    const int r0 = r_blk * 128;
    const int n0 = n_blk * 128;
    const int bb = n0 >> 12;
    const int t0 = n0 & (T_ - 1);
    const int m_base = (wave & 1) * 64;
    const int n_base = (wave >> 1) * 64;

    // staging: wave w stages rows 32w..32w+31 of each array; 2 DMA instrs/array
    const int lrow = lane >> 2;            // 0..15
    const int lg   = (lane & 3) * 8;       // ushort offset in row
    const size_t wA0 = (size_t)(r0 + wave * 32 + lrow) * 512 + lg;
    const size_t wA1 = wA0 + 16 * 512;
    const size_t xB0 = ((size_t)bb * TP + t0 + wave * 32 + lrow) * 256 + lg;
    const size_t xB1 = xB0 + 16 * 256;
    unsigned short* sAh = pA_hi + wave * 1024;   // wave-uniform LDS bases
    unsigned short* sAl = pA_lo + wave * 1024;

    floatx4 acc[4][4];
#pragma unroll
    for (int v = 0; v < 4; v++)
#pragma unroll
        for (int u = 0; u < 4; u++) acc[v][u] = (floatx4){0.f, 0.f, 0.f, 0.f};

    // prologue: stage A(0) and B(0) into buf0
    glds16(Whi + wA0, sAh);
    glds16(Whi + wA1, sAh + 512);
    glds16(Wlo + wA0, sAl);
    glds16(Wlo + wA1, sAl + 512);
    glds16(Xhi + xB0, pB_hi[0] + wave * 1024);
    glds16(Xhi + xB1, pB_hi[0] + wave * 1024 + 512);
    glds16(Xlo + xB0, pB_lo[0] + wave * 1024);
    glds16(Xlo + xB1, pB_lo[0] + wave * 1024 + 512);

    for (int i = 0; i < 16; i++) {
        const int cur = i & 1, nxt = cur ^ 1;
        __syncthreads();   // barrier1: drains in-flight DMA (overlapped with prev MFMAs)

        short8 ah[4], al[4], bh[4], bl[4];
#pragma unroll
        for (int v = 0; v < 4; v++) {
            int m = m_base + v * 16 + mr;
            ah[v] = *(const short8*)(pA_hi + m * 32 + q * 8);
            al[v] = *(const short8*)(pA_lo + m * 32 + q * 8);
        }
#pragma unroll
        for (int u = 0; u < 4; u++) {
            int n = n_base + u * 16 + mr;
            bh[u] = *(const short8*)(pB_hi[cur] + n * 32 + q * 8);
            bl[u] = *(const short8*)(pB_lo[cur] + n * 32 + q * 8);
        }
        __syncthreads();   // barrier2: cheap (vmcnt already 0; lgkm only)

        if (i < 15) {      // stage iter i+1: DMA in flight across the MFMA block below
            const int kk = (i + 1) * 32;
            glds16(Whi + wA0 + kk, sAh);
            glds16(Whi + wA1 + kk, sAh + 512);
            glds16(Wlo + wA0 + kk, sAl);
            glds16(Wlo + wA1 + kk, sAl + 512);
            glds16(Xhi + xB0 + kk, pB_hi[nxt] + wave * 1024);
            glds16(Xhi + xB1 + kk, pB_hi[nxt] + wave * 1024 + 512);
            glds16(Xlo + xB0 + kk, pB_lo[nxt] + wave * 1024);
            glds16(Xlo + xB1 + kk, pB_lo[nxt] + wave * 1024 + 512);
        }

#pragma unroll
        for (int v = 0; v < 4; v++)
#pragma unroll
            for (int u = 0; u < 4; u++)
                acc[v][u] = __builtin_amdgcn_mfma_f32_16x16x32_bf16(ah[v], bh[u], acc[v][u], 0, 0, 0);
#pragma unroll
        for (int v = 0; v < 4; v++)
#pragma unroll
            for (int u = 0; u < 4; u++)
                acc[v][u] = __builtin_amdgcn_mfma_f32_16x16x32_bf16(ah[v], bl[u], acc[v][u], 0, 0, 0);
#pragma unroll
        for (int v = 0; v < 4; v++)
#pragma unroll
            for (int u = 0; u < 4; u++)
                acc[v][u] = __builtin_amdgcn_mfma_f32_16x16x32_bf16(al[v], bh[u], acc[v][u], 0, 0, 0);
    }

    // ---------- epilogue ----------
    float* epf = smem_f;                 // [128][33]
    float* epz = smem_f + 4224;
    float* epo = smem_f + 8448;

    __syncthreads();                     // all fragment reads done
#pragma unroll
    for (int v = 0; v < 4; v++) {
        int cl = (m_base >> 2) + v * 4 + q;          // local channel 0..31
        int c  = (r0 >> 2) + cl;
        float bz = bias[c], bf_ = bias[256 + c], bo = bias[512 + c], bi = bias[768 + c];
#pragma unroll
        for (int u = 0; u < 4; u++) {
            int t_l = n_base + u * 16 + mr;
            float zv = ftanh(acc[v][u][0] + bz);
            float fv = fsig (acc[v][u][1] + bf_);
            float ov = fsig (acc[v][u][2] + bo);
            float iv = fsig (acc[v][u][3] + bi);
            int off = t_l * 33 + cl;
            epf[off] = fv;
            epz[off] = iv * zv;
            epo[off] = ov;
        }
    }
    __syncthreads();

    // coalesced stores: thread -> t_r = tid>>1, 16 consecutive c
    {
        const int t_r = tid >> 1;
        const int cb = (tid & 1) << 4;
        const size_t gbase = ((size_t)bb * T_ + t0 + t_r) * 256 + (r0 >> 2) + cb;
        const int lbase = t_r * 33 + cb;
#pragma unroll
        for (int j4 = 0; j4 < 4; j4++) {
            float4 vf = { epf[lbase + j4 * 4], epf[lbase + j4 * 4 + 1],
                          epf[lbase + j4 * 4 + 2], epf[lbase + j4 * 4 + 3] };
            *(float4*)&fw[gbase + j4 * 4] = vf;
        }
#pragma unroll
        for (int j4 = 0; j4 < 4; j4++) {
            float4 vz = { epz[lbase + j4 * 4], epz[lbase + j4 * 4 + 1],
                          epz[lbase + j4 * 4 + 2], epz[lbase + j4 * 4 + 3] };
            *(float4*)&izw[gbase + j4 * 4] = vz;
        }
#pragma unroll
        for (int j4 = 0; j4 < 4; j4++) {
            float4 vo = { epo[lbase + j4 * 4], epo[lbase + j4 * 4 + 1],
                          epo[lbase + j4 * 4 + 2], epo[lbase + j4 * 4 + 3] };
            *(float4*)&ow[gbase + j4 * 4] = vo;
        }
    }

    // fused scan phase 1: per-chunk (A = prod f, B = affine end) from LDS
    if (tid < 128) {
        const int chunk = tid >> 5, cc = tid & 31;
        float A = 1.0f, Bv = 0.0f;
        int base = (chunk * 32) * 33 + cc;
#pragma unroll 4
        for (int j = 0; j < 32; j++) {
            float f  = epf[base + j * 33];
            float iz = epz[base + j * 33];
            Bv = fmaf(f, Bv, iz);
            A *= f;
        }
        const int chunk_abs = (t0 >> 5) + chunk;
        const size_t aidx = ((size_t)bb * NCH + chunk_abs) * 256 + (r0 >> 2) + cc;
        Aw[aidx] = A;
        Bw[aidx] = Bv;
    }
}

// Phase 2: exclusive scan over chunk summaries; loads batched 16-wide to pipeline
__global__ void scan_phase2(const float* __restrict__ Aw, const float* __restrict__ Bw,
                            float* __restrict__ cw)
{
    int b = blockIdx.x, c = threadIdx.x;
    float carry = 0.0f;
    for (int ch0 = 0; ch0 < NCH; ch0 += 16) {
        float Ar[16], Br[16], cv[16];
#pragma unroll
        for (int j = 0; j < 16; j++) {
            size_t idx = ((size_t)(b * NCH + ch0 + j)) * CO + c;
            Ar[j] = Aw[idx];
            Br[j] = Bw[idx];
        }
#pragma unroll
        for (int j = 0; j < 16; j++) {
            cv[j] = carry;
            carry = fmaf(Ar[j], carry, Br[j]);
        }
#pragma unroll
        for (int j = 0; j < 16; j++)
            cw[((size_t)(b * NCH + ch0 + j)) * CO + c] = cv[j];
    }
}

// Phase 3: replay recurrence with carry, h = o*c, transpose [t][c] -> out[b][c][t]
__global__ void scan_phase3(const float* __restrict__ fw, const float* __restrict__ izw,
                            const float* __restrict__ ow, const float* __restrict__ cw,
                            float* __restrict__ out)
{
    __shared__ float hbuf[CL][257];
    int b = blockIdx.y, ch = blockIdx.x, c = threadIdx.x;
    float cs = cw[((size_t)(b * NCH + ch)) * CO + c];
    size_t base = ((size_t)(b * T_ + ch * CL)) * CO + c;
#pragma unroll 4
    for (int tt = 0; tt < CL; tt++) {
        float f  = fw[base + (size_t)tt * CO];
        float iz = izw[base + (size_t)tt * CO];
        float o  = ow[base + (size_t)tt * CO];
        cs = fmaf(f, cs, iz);
        hbuf[tt][c] = o * cs;
    }
    __syncthreads();
    int tt = threadIdx.x & 31;
    int cr = threadIdx.x >> 5;
#pragma unroll
    for (int w = 0; w < 32; w++) {
        int cc = cr + w * 8;
        out[((size_t)(b * CO + cc)) * T_ + ch * CL + tt] = hbuf[tt][cc];
    }
}

extern "C" void kernel_launch(void* const* d_in, const int* in_sizes, int n_in,
                              void* d_out, int out_size, void* d_ws, size_t ws_size,
                              hipStream_t stream) {
    const float* x    = (const float*)d_in[0];
    const float* W    = (const float*)d_in[1];
    const float* bias = (const float*)d_in[2];
    float* out = (float*)d_out;
    float* ws  = (float*)d_ws;

    unsigned short* Xhi = (unsigned short*)(ws + OFF_XHI);
    unsigned short* Xlo = (unsigned short*)(ws + OFF_XLO);
    unsigned short* Whi = (unsigned short*)(ws + OFF_WHI);
    unsigned short* Wlo = (unsigned short*)(ws + OFF_WLO);
    float* fw  = ws + OFF_F;
    float* izw = ws + OFF_IZ;
    float* ow  = ws + OFF_O;
    float* Aw  = ws + OFF_A;
    float* Bw  = ws + OFF_B;
    float* cw  = ws + OFF_C;

    convert_w_kernel<<<(O4 * KK) / 256, 256, 0, stream>>>(W, Whi, Wlo);
    convert_x_kernel<<<dim3(T_ / 64, CIN / 64, B_), 256, 0, stream>>>(x, Xhi, Xlo);
    gemm_mfma_kernel<<<(NN / 128) * (O4 / 128), 256, 0, stream>>>(
        Xhi, Xlo, Whi, Wlo, bias, fw, izw, ow, Aw, Bw);
    scan_phase2<<<B_, CO, 0, stream>>>(Aw, Bw, cw);
    scan_phase3<<<dim3(NCH, B_), CO, 0, stream>>>(fw, izw, ow, cw, out);
}

// Round 6
// 207.891 us; speedup vs baseline: 1.1176x; 1.1176x over previous
//
#include <hip/hip_runtime.h>
#include <hip/hip_fp16.h>

#define B_   8
#define CIN  256
#define T_   4096
#define TP   4097    // padded T (row 0 = zeros, row t+1 = x[t])
#define CO   256
#define O4   1024
#define KK   512
#define NN   32768   // B_*T_
#define NCH  128     // chunks along T
#define CL   32      // chunk length

// ws layout (float offsets)
#define OFF_XHI  0           // ushort [8][4097][256]
#define OFF_XLO  4195328
#define OFF_WHI  8390656     // ushort [1024][512]
#define OFF_WLO  8652800
#define OFF_F16  8914944     // ushort(f16) [8][4096][256]
#define OFF_IZ16 13109248
#define OFF_O16  17303552
#define OFF_A    21497856    // float [8][128][256]
#define OFF_B    21760000
#define OFF_C    22022144
// total 22,284,288 floats = 89.1 MB

typedef __attribute__((ext_vector_type(8))) short short8;
typedef __attribute__((ext_vector_type(4))) float floatx4;

__device__ __forceinline__ float fsig(float x)  { return 1.0f / (1.0f + __expf(-x)); }
__device__ __forceinline__ float ftanh(float x) { return 2.0f / (1.0f + __expf(-2.0f * x)) - 1.0f; }

__device__ __forceinline__ unsigned short bf16_rne(float v) {
    unsigned u = __float_as_uint(v);
    unsigned r = (u + 0x7fffu + ((u >> 16) & 1u)) >> 16;
    return (unsigned short)r;
}
__device__ __forceinline__ void split_bf16(float v, unsigned short& hi, unsigned short& lo) {
    hi = bf16_rne(v);
    float hf = __uint_as_float(((unsigned)hi) << 16);
    lo = bf16_rne(v - hf);
}

// async 16B/lane global->LDS DMA; lds base must be wave-uniform (dest = base + lane*16)
__device__ __forceinline__ void glds16(const unsigned short* g, unsigned short* l) {
    __builtin_amdgcn_global_load_lds(
        (const __attribute__((address_space(1))) unsigned*)g,
        (__attribute__((address_space(3))) unsigned*)l, 16, 0, 0);
}

// merged converts: bid<2048 -> W repack/split; bid>=2048 -> X transpose/split.
// W[o=g*256+c][i][j] -> Wa[r=c*4+g][k=j*256+i].  x[b][c][t] -> Xpad[b][t+1][c].
__global__ void convert_kernel(const float* __restrict__ W,
                               const float* __restrict__ x,
                               unsigned short* __restrict__ Whi,
                               unsigned short* __restrict__ Wlo,
                               unsigned short* __restrict__ Xhi,
                               unsigned short* __restrict__ Xlo) {
    __shared__ float tile[64][69];      // 69 mod 32 = 5 -> conflict-free both phases
    const int bid = blockIdx.x;
    const int tid = threadIdx.x;
    if (bid < 2048) {
        int e = bid * 256 + tid;        // 1024*512 elements
        int r = e >> 9, k = e & 511;
        int g = r & 3, c = r >> 2;
        int j = k >> 8, i = k & 255;
        float v = W[((size_t)((g << 8) + c)) * 512 + i * 2 + j];
        unsigned short hi, lo;
        split_bf16(v, hi, lo);
        Whi[e] = hi;
        Wlo[e] = lo;
        return;
    }
    const int b2 = bid - 2048;
    const int t0 = (b2 & 63) * 64;
    const int c0 = ((b2 >> 6) & 3) * 64;
    const int b  = b2 >> 8;

    {   // read: float4 along t, 16 rows per pass
        int j4 = (tid & 15) * 4, r16 = tid >> 4;
#pragma unroll
        for (int p = 0; p < 4; p++) {
            int i = p * 16 + r16;
            float4 v = *(const float4*)&x[((size_t)(b * 256 + c0 + i)) * T_ + t0 + j4];
            tile[i][j4] = v.x; tile[i][j4 + 1] = v.y;
            tile[i][j4 + 2] = v.z; tile[i][j4 + 3] = v.w;
        }
    }
    if (t0 == 0 && tid < 64) {   // zero pad row (x[-1] = 0)
        size_t z = (size_t)b * TP * 256 + c0 + tid;
        Xhi[z] = 0; Xlo[z] = 0;
    }
    __syncthreads();
    {   // write coalesced along c
        int i = tid & 63, jj = tid >> 6;
#pragma unroll
        for (int p = 0; p < 16; p++) {
            int t = jj * 16 + p;
            float v = tile[i][t];
            unsigned short hi, lo;
            split_bf16(v, hi, lo);
            size_t idx = ((size_t)b * TP + t0 + t + 1) * 256 + c0 + i;
            Xhi[idx] = hi;
            Xlo[idx] = lo;
        }
    }
}

// C[r=1024][n=32768] = Wa · Xb^T, split-bf16 MFMA (3 products), 128x128 tile, BK=32.
// A single-buffered LDS, B double-buffered, prefetch DMA issued before MFMA block.
// Epilogue: activations rounded through f16 -> LDS fp32 (consistent) -> f16 global
// stores + fused per-chunk scan summaries.
__launch_bounds__(256, 3)
__global__ void gemm_mfma_kernel(const unsigned short* __restrict__ Xhi,
                                 const unsigned short* __restrict__ Xlo,
                                 const unsigned short* __restrict__ Whi,
                                 const unsigned short* __restrict__ Wlo,
                                 const float* __restrict__ bias,
                                 __half* __restrict__ fw,
                                 __half* __restrict__ izw,
                                 __half* __restrict__ ow,
                                 float* __restrict__ Aw,
                                 float* __restrict__ Bw)
{
    __shared__ float smem_f[3 * 128 * 33];               // 50,688 B
    unsigned short* smem_us = (unsigned short*)smem_f;
    unsigned short* pA_hi = smem_us;                     // [128][32] contiguous, 8 KB
    unsigned short* pA_lo = smem_us + 4096;
    unsigned short* pB_hi[2] = { smem_us + 8192,  smem_us + 16384 };
    unsigned short* pB_lo[2] = { smem_us + 12288, smem_us + 20480 };

    const int tid  = threadIdx.x;
    const int wave = tid >> 6, lane = tid & 63;
    const int q = lane >> 4, mr = lane & 15;

    // grid map: XCD(=bid%8) keeps one X-tile for all 8 r-blocks; W L2-resident
    const int bid    = blockIdx.x;
    const int n_sub  = bid & 7;
    const int r_blk  = (bid >> 3) & 7;
    const int n_blk  = (bid >> 6) * 8 + n_sub;
    const int r0 = r_blk * 128;
    const int n0 = n_blk * 128;
    const int bb = n0 >> 12;
    const int t0 = n0 & (T_ - 1);
    const int m_base = (wave & 1) * 64;
    const int n_base = (wave >> 1) * 64;

    // staging: wave w stages rows 32w..32w+31 of each array; 2 DMA instrs/array
    const int lrow = lane >> 2;            // 0..15
    const int lg   = (lane & 3) * 8;       // ushort offset in row
    const size_t wA0 = (size_t)(r0 + wave * 32 + lrow) * 512 + lg;
    const size_t wA1 = wA0 + 16 * 512;
    const size_t xB0 = ((size_t)bb * TP + t0 + wave * 32 + lrow) * 256 + lg;
    const size_t xB1 = xB0 + 16 * 256;
    unsigned short* sAh = pA_hi + wave * 1024;   // wave-uniform LDS bases
    unsigned short* sAl = pA_lo + wave * 1024;

    floatx4 acc[4][4];
#pragma unroll
    for (int v = 0; v < 4; v++)
#pragma unroll
        for (int u = 0; u < 4; u++) acc[v][u] = (floatx4){0.f, 0.f, 0.f, 0.f};

    // prologue: stage A(0) and B(0) into buf0
    glds16(Whi + wA0, sAh);
    glds16(Whi + wA1, sAh + 512);
    glds16(Wlo + wA0, sAl);
    glds16(Wlo + wA1, sAl + 512);
    glds16(Xhi + xB0, pB_hi[0] + wave * 1024);
    glds16(Xhi + xB1, pB_hi[0] + wave * 1024 + 512);
    glds16(Xlo + xB0, pB_lo[0] + wave * 1024);
    glds16(Xlo + xB1, pB_lo[0] + wave * 1024 + 512);

    for (int i = 0; i < 16; i++) {
        const int cur = i & 1, nxt = cur ^ 1;
        __syncthreads();   // drains in-flight DMA (overlapped with prev MFMA block)

        short8 ah[4], al[4], bh[4], bl[4];
#pragma unroll
        for (int v = 0; v < 4; v++) {
            int m = m_base + v * 16 + mr;
            ah[v] = *(const short8*)(pA_hi + m * 32 + q * 8);
            al[v] = *(const short8*)(pA_lo + m * 32 + q * 8);
        }
#pragma unroll
        for (int u = 0; u < 4; u++) {
            int n = n_base + u * 16 + mr;
            bh[u] = *(const short8*)(pB_hi[cur] + n * 32 + q * 8);
            bl[u] = *(const short8*)(pB_lo[cur] + n * 32 + q * 8);
        }
        __syncthreads();   // cheap (vmcnt already 0; lgkm only)

        if (i < 15) {      // stage iter i+1: DMA in flight across the MFMA block below
            const int kk = (i + 1) * 32;
            glds16(Whi + wA0 + kk, sAh);
            glds16(Whi + wA1 + kk, sAh + 512);
            glds16(Wlo + wA0 + kk, sAl);
            glds16(Wlo + wA1 + kk, sAl + 512);
            glds16(Xhi + xB0 + kk, pB_hi[nxt] + wave * 1024);
            glds16(Xhi + xB1 + kk, pB_hi[nxt] + wave * 1024 + 512);
            glds16(Xlo + xB0 + kk, pB_lo[nxt] + wave * 1024);
            glds16(Xlo + xB1 + kk, pB_lo[nxt] + wave * 1024 + 512);
        }

#pragma unroll
        for (int v = 0; v < 4; v++)
#pragma unroll
            for (int u = 0; u < 4; u++)
                acc[v][u] = __builtin_amdgcn_mfma_f32_16x16x32_bf16(ah[v], bh[u], acc[v][u], 0, 0, 0);
#pragma unroll
        for (int v = 0; v < 4; v++)
#pragma unroll
            for (int u = 0; u < 4; u++)
                acc[v][u] = __builtin_amdgcn_mfma_f32_16x16x32_bf16(ah[v], bl[u], acc[v][u], 0, 0, 0);
#pragma unroll
        for (int v = 0; v < 4; v++)
#pragma unroll
            for (int u = 0; u < 4; u++)
                acc[v][u] = __builtin_amdgcn_mfma_f32_16x16x32_bf16(al[v], bh[u], acc[v][u], 0, 0, 0);
    }

    // ---------- epilogue ----------
    float* epf = smem_f;                 // [128][33]
    float* epz = smem_f + 4224;
    float* epo = smem_f + 8448;

    __syncthreads();                     // all fragment reads done
#pragma unroll
    for (int v = 0; v < 4; v++) {
        int cl = (m_base >> 2) + v * 4 + q;          // local channel 0..31
        int c  = (r0 >> 2) + cl;
        float bz = bias[c], bf_ = bias[256 + c], bo = bias[512 + c], bi = bias[768 + c];
#pragma unroll
        for (int u = 0; u < 4; u++) {
            int t_l = n_base + u * 16 + mr;
            // round each gate through f16 so summaries & replay are consistent
            float zv = ftanh(acc[v][u][0] + bz);
            float fv = __half2float(__float2half(fsig(acc[v][u][1] + bf_)));
            float ov = __half2float(__float2half(fsig(acc[v][u][2] + bo)));
            float iv = fsig(acc[v][u][3] + bi);
            float izv = __half2float(__float2half(iv * zv));
            int off = t_l * 33 + cl;
            epf[off] = fv;
            epz[off] = izv;
            epo[off] = ov;
        }
    }
    __syncthreads();

    // coalesced f16 stores: thread -> t_r = tid>>1, 16 consecutive c (32 B = 2x uint4)
    {
        const int t_r = tid >> 1;
        const int cb = (tid & 1) << 4;
        const size_t gbase = ((size_t)bb * T_ + t0 + t_r) * 256 + (r0 >> 2) + cb;
        const int lbase = t_r * 33 + cb;
        union { uint4 u[2]; __half h[16]; } pk;
#pragma unroll
        for (int j = 0; j < 16; j++) pk.h[j] = __float2half(epf[lbase + j]);
        *(uint4*)&fw[gbase] = pk.u[0];
        *(uint4*)&fw[gbase + 8] = pk.u[1];
#pragma unroll
        for (int j = 0; j < 16; j++) pk.h[j] = __float2half(epz[lbase + j]);
        *(uint4*)&izw[gbase] = pk.u[0];
        *(uint4*)&izw[gbase + 8] = pk.u[1];
#pragma unroll
        for (int j = 0; j < 16; j++) pk.h[j] = __float2half(epo[lbase + j]);
        *(uint4*)&ow[gbase] = pk.u[0];
        *(uint4*)&ow[gbase + 8] = pk.u[1];
    }

    // fused scan phase 1: per-chunk (A = prod f, B = affine end) from LDS
    if (tid < 128) {
        const int chunk = tid >> 5, cc = tid & 31;
        float A = 1.0f, Bv = 0.0f;
        int base = (chunk * 32) * 33 + cc;
#pragma unroll 4
        for (int j = 0; j < 32; j++) {
            float f  = epf[base + j * 33];
            float iz = epz[base + j * 33];
            Bv = fmaf(f, Bv, iz);
            A *= f;
        }
        const int chunk_abs = (t0 >> 5) + chunk;
        const size_t aidx = ((size_t)bb * NCH + chunk_abs) * 256 + (r0 >> 2) + cc;
        Aw[aidx] = A;
        Bw[aidx] = Bv;
    }
}

// Phase 2: exclusive scan over chunk summaries; loads batched 16-wide to pipeline
__global__ void scan_phase2(const float* __restrict__ Aw, const float* __restrict__ Bw,
                            float* __restrict__ cw)
{
    int b = blockIdx.x, c = threadIdx.x;
    float carry = 0.0f;
    for (int ch0 = 0; ch0 < NCH; ch0 += 16) {
        float Ar[16], Br[16], cv[16];
#pragma unroll
        for (int j = 0; j < 16; j++) {
            size_t idx = ((size_t)(b * NCH + ch0 + j)) * CO + c;
            Ar[j] = Aw[idx];
            Br[j] = Bw[idx];
        }
#pragma unroll
        for (int j = 0; j < 16; j++) {
            cv[j] = carry;
            carry = fmaf(Ar[j], carry, Br[j]);
        }
#pragma unroll
        for (int j = 0; j < 16; j++)
            cw[((size_t)(b * NCH + ch0 + j)) * CO + c] = cv[j];
    }
}

// Phase 3: replay recurrence with carry, h = o*c, transpose [t][c] -> out[b][c][t]
__global__ void scan_phase3(const __half* __restrict__ fw, const __half* __restrict__ izw,
                            const __half* __restrict__ ow, const float* __restrict__ cw,
                            float* __restrict__ out)
{
    __shared__ float hbuf[CL][257];
    int b = blockIdx.y, ch = blockIdx.x, c = threadIdx.x;
    float cs = cw[((size_t)(b * NCH + ch)) * CO + c];
    size_t base = ((size_t)(b * T_ + ch * CL)) * CO + c;
#pragma unroll 4
    for (int tt = 0; tt < CL; tt++) {
        float f  = __half2float(fw[base + (size_t)tt * CO]);
        float iz = __half2float(izw[base + (size_t)tt * CO]);
        float o  = __half2float(ow[base + (size_t)tt * CO]);
        cs = fmaf(f, cs, iz);
        hbuf[tt][c] = o * cs;
    }
    __syncthreads();
    int tt = threadIdx.x & 31;
    int cr = threadIdx.x >> 5;
#pragma unroll
    for (int w = 0; w < 32; w++) {
        int cc = cr + w * 8;
        out[((size_t)(b * CO + cc)) * T_ + ch * CL + tt] = hbuf[tt][cc];
    }
}

extern "C" void kernel_launch(void* const* d_in, const int* in_sizes, int n_in,
                              void* d_out, int out_size, void* d_ws, size_t ws_size,
                              hipStream_t stream) {
    const float* x    = (const float*)d_in[0];
    const float* W    = (const float*)d_in[1];
    const float* bias = (const float*)d_in[2];
    float* out = (float*)d_out;
    float* ws  = (float*)d_ws;

    unsigned short* Xhi = (unsigned short*)(ws + OFF_XHI);
    unsigned short* Xlo = (unsigned short*)(ws + OFF_XLO);
    unsigned short* Whi = (unsigned short*)(ws + OFF_WHI);
    unsigned short* Wlo = (unsigned short*)(ws + OFF_WLO);
    __half* fw  = (__half*)(ws + OFF_F16);
    __half* izw = (__half*)(ws + OFF_IZ16);
    __half* ow  = (__half*)(ws + OFF_O16);
    float* Aw  = ws + OFF_A;
    float* Bw  = ws + OFF_B;
    float* cw  = ws + OFF_C;

    convert_kernel<<<4096, 256, 0, stream>>>(W, x, Whi, Wlo, Xhi, Xlo);
    gemm_mfma_kernel<<<(NN / 128) * (O4 / 128), 256, 0, stream>>>(
        Xhi, Xlo, Whi, Wlo, bias, fw, izw, ow, Aw, Bw);
    scan_phase2<<<B_, CO, 0, stream>>>(Aw, Bw, cw);
    scan_phase3<<<dim3(NCH, B_), CO, 0, stream>>>(fw, izw, ow, cw, out);
}